// Round 3
// baseline (564.626 us; speedup 1.0000x reference)
//
#include <hip/hip_runtime.h>
#include <math.h>

typedef __attribute__((ext_vector_type(8))) short bf16x8;
typedef __attribute__((ext_vector_type(4))) float f32x4;
typedef __attribute__((ext_vector_type(4))) unsigned short u16x4;

__device__ inline unsigned short f2bf(float f) {
    union { float f; unsigned u; } v; v.f = f;
    unsigned r = v.u + 0x7FFFu + ((v.u >> 16) & 1u);   // RNE
    return (unsigned short)(r >> 16);
}
__device__ inline float bf2f(unsigned short h) {
    union { unsigned u; float f; } v; v.u = ((unsigned)h) << 16;
    return v.f;
}

// async 16B global -> LDS. LDS dest is wave-uniform base; HW spreads lane*16 (m104).
__device__ inline void load_lds16(const void* g, void* l) {
    __builtin_amdgcn_global_load_lds(
        (const __attribute__((address_space(1))) unsigned int*)g,
        (__attribute__((address_space(3))) unsigned int*)l,
        16, 0, 0);
}

// One-launch f32->bf16 convert of 4 segments (seg 3 zero-padded nDs..nDd).
__global__ __launch_bounds__(256) void convert_all(
    const float* __restrict__ sA, unsigned short* __restrict__ dA, long nA,
    const float* __restrict__ sB, unsigned short* __restrict__ dB, long nB,
    const float* __restrict__ sC, unsigned short* __restrict__ dC, long nC,
    const float* __restrict__ sD, unsigned short* __restrict__ dD, long nDs, long nDd)
{
    long i = ((long)blockIdx.x * 256 + threadIdx.x) * 4;
    const float* s; unsigned short* d; long nsrc;
    if (i < nA)              { s = sA + i; d = dA + i; nsrc = nA - i; }
    else if ((i -= nA) < nB) { s = sB + i; d = dB + i; nsrc = nB - i; }
    else if ((i -= nB) < nC) { s = sC + i; d = dC + i; nsrc = nC - i; }
    else if ((i -= nC) < nDd){ s = sD + i; d = dD + i; nsrc = nDs - i; }
    else return;
    float4 v = make_float4(0.f, 0.f, 0.f, 0.f);
    if (nsrc >= 4) v = *(const float4*)s;
    u16x4 o;
    o[0] = f2bf(v.x); o[1] = f2bf(v.y); o[2] = f2bf(v.z); o[3] = f2bf(v.w);
    *(u16x4*)d = o;
}

// ---------------------------------------------------------------------------
// gemm1: out = A(M x K) * B^T(Npad x K), bf16 in.  64x128 tile, BK=64,
// 256 thr = 4 waves (1m x 4n: wave = 64m x 32n, acc[4][2]).  LDS 24 KiB,
// ~90 VGPR -> ~5 resident blocks/CU; grid (M/64)*(Npad/128) = 1088 for gemm1's
// shape (was 544 at 128x128 -> half-idle machine).
// Epilogue (swapped-operand MFMA: m=lane&15, n=quad*4+reg consecutive):
//   n0 <  nsplit: bf16 u16x4 store, ld=nsplit, bias0
//   n0 >= nsplit: f32x4 softplus(v)+1e-3, ld=Npad-nsplit, bias1
// Staging: concat(A 64 rows, B 128 rows) = 192 rows / 4 waves = 6 chunks of
// 8 rows per wave; chunk-XOR swizzle (LDS[r][c] = G[r][c ^ (r&7)], free 2-way).
// ---------------------------------------------------------------------------
__global__ __launch_bounds__(256) void gemm1_k(
    const unsigned short* __restrict__ A, const unsigned short* __restrict__ Bm,
    const float* __restrict__ bias0, const float* __restrict__ bias1,
    unsigned short* __restrict__ out0, float* __restrict__ out1,
    int M, int Npad, int K, int nsplit)
{
    __shared__ __align__(16) unsigned short As[64 * 64];
    __shared__ __align__(16) unsigned short Bs[128 * 64];

    const int nblk = Npad >> 7;
    const int mt = blockIdx.x / nblk;
    const int nt = blockIdx.x - mt * nblk;
    const int m0 = mt << 6;
    const int n0 = nt << 7;

    const int tid  = threadIdx.x;
    const int lane = tid & 63;
    const int wid  = tid >> 6;       // 0..3 -> n-offset wid*32
    const int quad = lane >> 4;
    const int l15  = lane & 15;
    const int l7   = l15 & 7;
    const int lrow = lane >> 3;
    const int lcol = ((lane & 7) ^ lrow) << 3;

    const unsigned short* Ab = A  + (size_t)(m0 + lrow) * K + lcol;
    const unsigned short* Bb = Bm + (size_t)(n0 + lrow) * K + lcol;

    f32x4 acc[4][2];
    #pragma unroll
    for (int i = 0; i < 4; ++i)
        #pragma unroll
        for (int j = 0; j < 2; ++j)
            acc[i][j] = f32x4{0.f, 0.f, 0.f, 0.f};

    for (int kt = 0; kt < K; kt += 64) {
        __syncthreads();
        #pragma unroll
        for (int i = 0; i < 6; ++i) {
            const int r0 = wid * 48 + i * 8;       // 0..191, wave-uniform
            if (r0 < 64) load_lds16(Ab + (size_t)r0 * K + kt, &As[r0 * 64]);
            else         load_lds16(Bb + (size_t)(r0 - 64) * K + kt, &Bs[(r0 - 64) * 64]);
        }
        __syncthreads();

        #pragma unroll
        for (int kk = 0; kk < 64; kk += 32) {
            const int kq = kk >> 3;
            bf16x8 af[4], bfv[2];
            #pragma unroll
            for (int mi = 0; mi < 4; ++mi)
                af[mi] = *(const bf16x8*)&As[(mi * 16 + l15) * 64
                                             + (((kq + quad) ^ l7) << 3)];
            #pragma unroll
            for (int ni = 0; ni < 2; ++ni)
                bfv[ni] = *(const bf16x8*)&Bs[(wid * 32 + ni * 16 + l15) * 64
                                              + (((kq + quad) ^ l7) << 3)];
            #pragma unroll
            for (int mi = 0; mi < 4; ++mi)
                #pragma unroll
                for (int ni = 0; ni < 2; ++ni)
                    acc[mi][ni] = __builtin_amdgcn_mfma_f32_16x16x32_bf16(
                        bfv[ni], af[mi], acc[mi][ni], 0, 0, 0);
        }
    }

    if (n0 < nsplit) {
        #pragma unroll
        for (int ni = 0; ni < 2; ++ni) {
            const int nb = n0 + wid * 32 + ni * 16 + (quad << 2);
            const float4 bv = *(const float4*)&bias0[nb];
            #pragma unroll
            for (int mi = 0; mi < 4; ++mi) {
                const int m = m0 + mi * 16 + l15;
                u16x4 ov;
                ov[0] = f2bf(acc[mi][ni][0] + bv.x);
                ov[1] = f2bf(acc[mi][ni][1] + bv.y);
                ov[2] = f2bf(acc[mi][ni][2] + bv.z);
                ov[3] = f2bf(acc[mi][ni][3] + bv.w);
                *(u16x4*)&out0[(size_t)m * nsplit + nb] = ov;
            }
        }
    } else {
        const int ld1 = Npad - nsplit;
        #pragma unroll
        for (int ni = 0; ni < 2; ++ni) {
            const int nb = n0 + wid * 32 + ni * 16 + (quad << 2) - nsplit;
            const float4 bv = *(const float4*)&bias1[nb];
            #pragma unroll
            for (int mi = 0; mi < 4; ++mi) {
                const int m = m0 + mi * 16 + l15;
                f32x4 v;
                #pragma unroll
                for (int r = 0; r < 4; ++r) {
                    float x = acc[mi][ni][r] + ((const float*)&bv)[r];
                    float sp = (x > 20.f) ? x : log1pf(expf(x));
                    v[r] = sp + 1e-3f;
                }
                *(f32x4*)&out1[(size_t)m * ld1 + nb] = v;
            }
        }
    }
}

// ---------------------------------------------------------------------------
// gemm2: logits = (A(M x K) * B^T(Npad x K) + bias)/1.5, f32 NT stores.
// 128x256 tile, BK=64, 512 thr = 8 waves (2m x 4n: wave = 64m x 64n, acc[4][4]).
// LDS 48 KiB; __launch_bounds__(512,4) caps VGPR at 128 -> 2 resident
// blocks/CU (16 waves) — cross-block overlap hides barrier drains (m97/m114
// mechanism), while the 256-wide B-tile halves staged bytes per FLOP vs 128^2.
// Staging: concat(A 128, B 256) = 384 rows / 8 waves = 6 chunks of 8 rows.
// SWZ: XCD-locality, n-tiles innermost per XCD (A-tile L2 reuse x4).
// ---------------------------------------------------------------------------
template <bool SWZ>
__global__ __launch_bounds__(512, 4) void gemm2_k(
    const unsigned short* __restrict__ A, const unsigned short* __restrict__ Bm,
    const float* __restrict__ bias0, float* __restrict__ out,
    int M, int Npad, int Nreal, int K)
{
    __shared__ __align__(16) unsigned short As[128 * 64];
    __shared__ __align__(16) unsigned short Bs[256 * 64];

    const int nblk = Npad >> 8;
    int mt, nt;
    if constexpr (SWZ) {
        const int per = (M >> 7) >> 3;      // m-tiles per XCD
        const int x = blockIdx.x & 7;
        const int j = blockIdx.x >> 3;
        const int jm = j / nblk;
        mt = x * per + jm;
        nt = j - jm * nblk;
    } else {
        mt = blockIdx.x / nblk;
        nt = blockIdx.x - mt * nblk;
    }
    const int m0 = mt << 7;
    const int n0 = nt << 8;

    const int tid  = threadIdx.x;
    const int lane = tid & 63;
    const int wid  = tid >> 6;       // 0..7
    const int wmh  = wid >> 2;       // 0..1 -> m-offset wmh*64
    const int wnq  = wid & 3;        // 0..3 -> n-offset wnq*64
    const int quad = lane >> 4;
    const int l15  = lane & 15;
    const int l7   = l15 & 7;
    const int lrow = lane >> 3;
    const int lcol = ((lane & 7) ^ lrow) << 3;

    const unsigned short* Ab = A  + (size_t)(m0 + lrow) * K + lcol;
    const unsigned short* Bb = Bm + (size_t)(n0 + lrow) * K + lcol;

    f32x4 acc[4][4];
    #pragma unroll
    for (int i = 0; i < 4; ++i)
        #pragma unroll
        for (int j = 0; j < 4; ++j)
            acc[i][j] = f32x4{0.f, 0.f, 0.f, 0.f};

    for (int kt = 0; kt < K; kt += 64) {
        __syncthreads();
        #pragma unroll
        for (int i = 0; i < 6; ++i) {
            const int r0 = wid * 48 + i * 8;       // 0..383, wave-uniform
            if (r0 < 128) load_lds16(Ab + (size_t)r0 * K + kt, &As[r0 * 64]);
            else          load_lds16(Bb + (size_t)(r0 - 128) * K + kt, &Bs[(r0 - 128) * 64]);
        }
        __syncthreads();

        #pragma unroll
        for (int kk = 0; kk < 64; kk += 32) {
            const int kq = kk >> 3;
            bf16x8 af[4], bfv[4];
            #pragma unroll
            for (int mi = 0; mi < 4; ++mi)
                af[mi] = *(const bf16x8*)&As[(wmh * 64 + mi * 16 + l15) * 64
                                             + (((kq + quad) ^ l7) << 3)];
            #pragma unroll
            for (int ni = 0; ni < 4; ++ni)
                bfv[ni] = *(const bf16x8*)&Bs[(wnq * 64 + ni * 16 + l15) * 64
                                              + (((kq + quad) ^ l7) << 3)];
            #pragma unroll
            for (int mi = 0; mi < 4; ++mi)
                #pragma unroll
                for (int ni = 0; ni < 4; ++ni)
                    acc[mi][ni] = __builtin_amdgcn_mfma_f32_16x16x32_bf16(
                        bfv[ni], af[mi], acc[mi][ni], 0, 0, 0);
        }
    }

    // epilogue: m = ...+l15 (row), n = ...+quad*4+reg (4 consecutive) -> f32x4
    #pragma unroll
    for (int ni = 0; ni < 4; ++ni) {
        const int nb = n0 + wnq * 64 + ni * 16 + (quad << 2);
        if (nb < Nreal) {                     // Nreal%4==0: all-or-nothing
            const float4 bv = *(const float4*)&bias0[nb];
            #pragma unroll
            for (int mi = 0; mi < 4; ++mi) {
                const int m = m0 + wmh * 64 + mi * 16 + l15;
                f32x4 v;
                v[0] = (acc[mi][ni][0] + bv.x) * (1.0f / 1.5f);
                v[1] = (acc[mi][ni][1] + bv.y) * (1.0f / 1.5f);
                v[2] = (acc[mi][ni][2] + bv.z) * (1.0f / 1.5f);
                v[3] = (acc[mi][ni][3] + bv.w) * (1.0f / 1.5f);
                __builtin_nontemporal_store(v, (f32x4*)&out[(size_t)m * Nreal + nb]);
            }
        }
    }
}

// pre[b,s,d] = f[b,d] + sum_r L[b,d,r]*z[b,s,r] + diag[b,d]*nd[b,s,d], bf16.
// One b per block; 2 s-halves x 128 threads; thread owns 4 consecutive d.
// s-loop unrolled x4 (4 independent nd loads in flight) and nd is read
// NONTEMPORAL (128 MB streamed once; keeps `pre` L2/L3-resident for gemm2).
__global__ __launch_bounds__(256) void sample_kernel(
    const float* __restrict__ features, const unsigned short* __restrict__ lr_cov,
    const float* __restrict__ diag, const float* __restrict__ nz_lr,
    const float* __restrict__ nz_diag, unsigned short* __restrict__ pre,
    int S, int D)
{
    const int tid = threadIdx.x;
    const int b   = blockIdx.x;
    const int sh  = tid >> 7;
    const int t   = tid & 127;
    const int d0  = t << 2;

    __shared__ __align__(16) float snz[64 * 16];
    ((float4*)snz)[tid] = ((const float4*)(nz_lr + (size_t)b * S * 16))[tid];

    float4 f  = *(const float4*)(features + (size_t)b * D + d0);
    float4 dg = *(const float4*)(diag + (size_t)b * D + d0);
    float L[4][16];
    const unsigned short* lp = lr_cov + (size_t)b * D * 16 + (size_t)d0 * 16;
    #pragma unroll
    for (int j = 0; j < 4; ++j) {
        bf16x8 a = *(const bf16x8*)(lp + j * 16);
        bf16x8 c = *(const bf16x8*)(lp + j * 16 + 8);
        #pragma unroll
        for (int r = 0; r < 8; ++r) {
            L[j][r]     = bf2f((unsigned short)a[r]);
            L[j][8 + r] = bf2f((unsigned short)c[r]);
        }
    }
    __syncthreads();

    const int s0 = sh * (S >> 1);
    const float* ndp = nz_diag + (size_t)b * S * D + (size_t)s0 * D + d0;
    unsigned short* pp = pre + (size_t)b * S * D + (size_t)s0 * D + d0;
    const int SH = S >> 1;
    for (int s = 0; s < SH; s += 4) {
        f32x4 nd[4];
        #pragma unroll
        for (int j = 0; j < 4; ++j)
            nd[j] = __builtin_nontemporal_load((const f32x4*)(ndp + (size_t)(s + j) * D));
        float o[4][4];
        #pragma unroll
        for (int j = 0; j < 4; ++j) {
            o[j][0] = f.x + dg.x * nd[j][0];
            o[j][1] = f.y + dg.y * nd[j][1];
            o[j][2] = f.z + dg.z * nd[j][2];
            o[j][3] = f.w + dg.w * nd[j][3];
        }
        #pragma unroll
        for (int r = 0; r < 16; ++r) {
            #pragma unroll
            for (int j = 0; j < 4; ++j) {
                const float zv = snz[(s0 + s + j) * 16 + r];
                o[j][0] += L[0][r] * zv;
                o[j][1] += L[1][r] * zv;
                o[j][2] += L[2][r] * zv;
                o[j][3] += L[3][r] * zv;
            }
        }
        #pragma unroll
        for (int j = 0; j < 4; ++j) {
            u16x4 ov;
            ov[0] = f2bf(o[j][0]); ov[1] = f2bf(o[j][1]);
            ov[2] = f2bf(o[j][2]); ov[3] = f2bf(o[j][3]);
            *(u16x4*)(pp + (size_t)(s + j) * D) = ov;
        }
    }
}

extern "C" void kernel_launch(void* const* d_in, const int* in_sizes, int n_in,
                              void* d_out, int out_size, void* d_ws, size_t ws_size,
                              hipStream_t stream)
{
    const float* features = (const float*)d_in[0];
    const float* W_cov    = (const float*)d_in[1];
    const float* b_cov    = (const float*)d_in[2];
    const float* W_diag   = (const float*)d_in[3];
    const float* b_diag   = (const float*)d_in[4];
    const float* W_cls    = (const float*)d_in[5];
    const float* b_cls    = (const float*)d_in[6];
    const float* nz_diag  = (const float*)d_in[7];
    const float* nz_lr    = (const float*)d_in[8];

    const int D    = in_sizes[4];            // 512
    const int DR   = in_sizes[2];            // 8192
    const int B    = in_sizes[0] / D;        // 1024
    const int S    = in_sizes[7] / (B * D);  // 64
    const int C    = in_sizes[6];            // 1000
    const int M    = B * S;                  // 65536
    const int Cpad = (C + 255) & ~255;       // 1024
    const int Ncat = DR + D;                 // 8704

    char* ws = (char*)d_ws;
    unsigned short* lrcov = (unsigned short*)ws;                      // B*DR bf16
    float*          diag  = (float*)(ws + (size_t)B * DR * 2);        // B*D f32
    unsigned short* wclsb = (unsigned short*)((char*)diag + (size_t)B * D * 4); // Cpad*D
    char* X = (char*)wclsb + (size_t)Cpad * D * 2;
    unsigned short* featb = (unsigned short*)X;                       // B*D (dead after gemm1)
    unsigned short* wcatb = featb + (size_t)B * D;                    // Ncat*D (dead after gemm1)
    unsigned short* pre   = (unsigned short*)X;                       // M*D (overlays featb+wcatb)

    // 1) all f32 -> bf16 converts in one launch
    {
        long n1 = (long)DR * D;
        long n2 = (long)D * D;
        long n3 = (long)B * D;
        long n4s = (long)C * D, n4d = (long)Cpad * D;
        long total = n1 + n2 + n3 + n4d;
        convert_all<<<dim3((unsigned)(total / 1024)), 256, 0, stream>>>(
            W_cov, wcatb, n1,
            W_diag, wcatb + n1, n2,
            features, featb, n3,
            W_cls, wclsb, n4s, n4d);
    }

    // 2) fused: lr_cov (bf16) + diag (softplus f32) in one 64x128-tile GEMM
    gemm1_k<<<dim3((B / 64) * (Ncat / 128)), 256, 0, stream>>>(
        featb, wcatb, b_cov, b_diag, lrcov, diag, B, Ncat, D, DR);

    // 3) pre_logits (bf16)
    sample_kernel<<<dim3(B), 256, 0, stream>>>(
        features, lrcov, diag, nz_lr, nz_diag, pre, S, D);

    // 4) logits = (pre @ W_cls^T + b_cls) / 1.5 — 128x256-tile, 2 blocks/CU
    gemm2_k<true><<<dim3((M / 128) * (Cpad / 256)), 512, 0, stream>>>(
        pre, wclsb, b_cls, (float*)d_out, M, Cpad, C, D);
}